// Round 13
// baseline (5160.917 us; speedup 1.0000x reference)
//
#include <hip/hip_runtime.h>
#include <cmath>

// RNN with Dale's-law recurrent matrix, B=128, S=2000, H=512, I=8, O=2.
// 16 persistent blocks = 8 batch-groups (M=16) x 2 j-slices (256 j each), 512 thr.
// Base = round-10 WIN (4531us): data-only sc0 XCD-local exchange, agent-scope
// flags (r11 sc0-flag spin-poll hung: L1 staleness; flags stay agent-scope).
// ONE delta (r12 retry; r12 was a pure compile error -- global_load offset:
// immediate is 13-bit SIGNED, max +4095; fix = two base regs, offsets 0..3072):
// ELIMINATE barB -- C-phase goes register-direct.
//   - Each wave loads the WHOLE peer half (8 x 16B/lane, sc0, two asm blocks
//     with bases srcrf and srcrf+4096, offsets 0/1024/2048/3072). Peer data is
//     L2-resident (r10: WRITE 3.4MB); 64KB/block/step from L2 is free vs 34TB/s.
//     C-phase MFMAs consume registers only: no LDS reads, no barB.
//   - 16B/thread LDS staging kept (sole consumer: w7 out-GEMM + epilogue);
//     ordering collapses onto barD.
//   - ldsA -> 3 slots (48KB): w7 reads r_{s-1} (slot s3p) while staging writes
//     s3c and D writes s3n -- distinct slots, race structurally gone; all
//     cross-step orderings via barD as before.
//   - ldsIN -> ping-pong one step ahead (r9's correct mechanism): inp row s+1
//     loaded PRE-POLL (rides flag wait, r9 lesson), written post-drain, read
//     at D(s+1) across barD.
//   Accumulation order bit-identical -> absmax unchanged. Rule-18 fences
//   (sched_barrier(0) around the vmcnt(0)) keep register MFMAs behind the drain.

constexpr int kS = 2000, kI = 8, kH = 512, kO = 2;
constexpr float kNoiseStd = 0.0005f, kAlpha = 0.1f;

constexpr int GROUPS = 8;   // batch groups of 16
constexpr int NSPL   = 2;   // j-slices (blocks) per group
constexpr int JS     = 256; // j per block
constexpr int NTHR   = 512; // 8 waves; wave w owns j in [w*32, w*32+32)
constexpr int NBLK   = GROUPS * NSPL;  // 16 blocks
constexpr int RSLOT  = 8192;           // halves per (slot,group) = 16KB

typedef _Float16 half8  __attribute__((ext_vector_type(8)));
typedef float    floatx4 __attribute__((ext_vector_type(4)));
typedef unsigned uintx4  __attribute__((ext_vector_type(4)));

#define MFMA16(A, B, C) __builtin_amdgcn_mfma_f32_16x16x32_f16((A), (B), (C), 0, 0, 0)
#define PIN8(a) asm volatile("" : "+v"((a)[0]), "+v"((a)[1]), "+v"((a)[2]), "+v"((a)[3]), \
                                   "+v"((a)[4]), "+v"((a)[5]), "+v"((a)[6]), "+v"((a)[7]))

static __device__ __forceinline__ unsigned ld_flag(const unsigned* p) {
  return __hip_atomic_load(p, __ATOMIC_RELAXED, __HIP_MEMORY_SCOPE_AGENT);
}
static __device__ __forceinline__ void st_flag(unsigned* p, unsigned v) {
  __hip_atomic_store(p, v, __ATOMIC_RELAXED, __HIP_MEMORY_SCOPE_AGENT);
}

// tanh(x) = sign(x) * (1 - 2/(exp2(2*log2e*|x|)+1)); overflow saturates to 1.
static __device__ __forceinline__ float fast_tanh(float x) {
  const float ax = __builtin_fabsf(x);
  const float e = __builtin_amdgcn_exp2f(2.8853900817779268f * ax);
  const float r = __builtin_amdgcn_rcpf(e + 1.0f);
  return __builtin_copysignf(__builtin_fmaf(-2.0f, r, 1.0f), x);
}

__global__ __launch_bounds__(NTHR, 1) void rnn_k(
    const float* __restrict__ inp,   // [B,S,I]
    const float* __restrict__ noise, // [B,S,H]
    const float* __restrict__ wi,    // [I,H]
    const float* __restrict__ wexc,  // [384,H]
    const float* __restrict__ winh,  // [128,H]
    const float* __restrict__ wout,  // [H,O]
    const float* __restrict__ h0,    // [H]
    float* __restrict__ out,         // [B,S,O]
    _Float16* __restrict__ rbuf,     // [2][GROUPS][RSLOT]
    unsigned* __restrict__ flags)    // [2][GROUPS][NSPL]
{
  const int bid = blockIdx.x;
  const int g = bid & 7;        // batch group
  const int c = bid >> 3;       // j-slice index (0 or 1)
  const int tid = threadIdx.x;
  const int w = tid >> 6;       // wave (0..7)
  const int lane = tid & 63;
  const int l15 = lane & 15;
  const int lhi = lane >> 4;

  const int j0 = c * JS + w * 32 + l15;  // this lane's two output columns
  const int j1 = j0 + 16;
  const int ktp = c * 8 + w;             // this wave's kt chunk in the r layout
  const int jsub0 = l15 >> 3, jsub1 = 2 + (l15 >> 3), vv = l15 & 7;

  unsigned myXcd;
  asm volatile("s_getreg_b32 %0, hwreg(HW_REG_XCC_ID)" : "=s"(myXcd));
  myXcd &= 0x7fffu;

  __shared__ _Float16 ldsA[3][RSLOT];    // 48KB: 3-slot full r tiles (16KB each)
  __shared__ half8 ws_wout[16][64];      // 16KB (used by c==0)
  __shared__ float ldsIN[2][16][kI];     // inp rows, ping-pong one step ahead

  // ---- wrec B-fragments in registers, own/peer k-half, static indices only ----
  half8 wfo0[8], wfo1[8], wfp0[8], wfp1[8];
  {
    const float* wr0 = (j0 < 384) ? (wexc + (size_t)j0 * kH) : (winh + (size_t)(j0 - 384) * kH);
    const float* wr1 = (j1 < 384) ? (wexc + (size_t)j1 * kH) : (winh + (size_t)(j1 - 384) * kH);
    const int ko = (c * 8) * 32 + lhi * 8;
    const int kp = ((c ^ 1) * 8) * 32 + lhi * 8;
#pragma unroll
    for (int t = 0; t < 8; ++t) {
      half8 a, b, d, e;
#pragma unroll
      for (int v = 0; v < 8; ++v) {
        a[v] = (_Float16)wr0[ko + t * 32 + v];
        b[v] = (_Float16)wr1[ko + t * 32 + v];
        d[v] = (_Float16)wr0[kp + t * 32 + v];
        e[v] = (_Float16)wr1[kp + t * 32 + v];
      }
      wfo0[t] = a; wfo1[t] = b; wfp0[t] = d; wfp1[t] = e;
    }
    PIN8(wfo0); PIN8(wfo1); PIN8(wfp0); PIN8(wfp1);
  }

  float wiv0[8], wiv1[8];
#pragma unroll
  for (int i = 0; i < 8; ++i) { wiv0[i] = wi[i * kH + j0]; wiv1[i] = wi[i * kH + j1]; }

  if (c == 0 && w < 4) {
#pragma unroll
    for (int t = 0; t < 4; ++t) {
      const int kt = w * 4 + t;
      const int k0 = kt * 32 + lhi * 8;
      half8 hv;
#pragma unroll
      for (int v = 0; v < 8; ++v)
        hv[v] = (l15 < kO) ? (_Float16)wout[(size_t)(k0 + v) * kO + l15] : (_Float16)0.f;
      ws_wout[kt][lane] = hv;
    }
  }

  // stage inp row 0 into ldsIN[0] (read at D(0); init barrier orders it)
  if (w == 2 || w == 3) {
    const int ii = tid - 128;
    ldsIN[0][ii >> 3][ii & 7] = inp[((size_t)(g * 16 + (ii >> 3)) * kS + 0) * kI + (ii & 7)];
  }

  // ---- init h, write r_0 own chunk into ldsA slot 0, publish (LLC) ----
  float hq0[4], hq1[4];
  {
    const float h00 = h0[j0], h01 = h0[j1];
#pragma unroll
    for (int q = 0; q < 4; ++q) { hq0[q] = h00; hq1[q] = h01; }
    const _Float16 r00 = (_Float16)fast_tanh(h00);
    const _Float16 r01 = (_Float16)fast_tanh(h01);
#pragma unroll
    for (int q = 0; q < 4; ++q) {
      const int bb = lhi * 4 + q;
      ldsA[0][ktp * 512 + (bb + 16 * jsub0) * 8 + vv] = r00;
      ldsA[0][ktp * 512 + (bb + 16 * jsub1) * 8 + vv] = r01;
    }
    const uintx4 pub = *(const uintx4*)((const char*)&ldsA[0][0] + ktp * 1024 + lane * 16);
    char* dst = (char*)rbuf + (size_t)(0 * GROUPS + g) * (RSLOT * 2) + ktp * 1024 + lane * 16;
    asm volatile("global_store_dwordx4 %0, %1, off sc0 sc1" :: "v"(dst), "v"(pub) : "memory");
  }
  __syncthreads();  // drains vmcnt(0): publish complete
  if (tid == 0) st_flag(&flags[(0 * GROUPS + g) * NSPL + c], (myXcd << 16) | 1u);

  // ---- handshake: read peer XCD from its init flag (doubles as s=0 pre-poll) ----
  bool sameXcd;
  {
    unsigned pf;
    const unsigned* fp = &flags[(0 * GROUPS + g) * NSPL + (c ^ 1)];
    do { pf = ld_flag(fp); } while ((pf & 0xffffu) < 1u);
    sameXcd = ((pf >> 16) == myXcd);
    asm volatile("" ::: "memory");
  }

  const char* base = (const char*)&ldsA[0][0];
  int s3p = 2, s3c = 0, s3n = 1;  // LDS slots of r_{s-1}, r_s, r_{s+1}

  // ---- main loop ----
  for (int s = 0; s < kS; ++s) {
    const int cur = s & 1;
    const bool lastS = (s == kS - 1);
    if (lastS && c != 0) break;  // c==1 published r_1999 at iter 1998; done

    // deferred out-GEMM: row s-1 from ldsA slot s3p (full r_{s-1}; slot is
    // untouched this step -- staging writes s3c, D writes s3n). Hidden under
    // the flag wait; ordering via barD(s-1)/barD(s).
    if (c == 0 && w == 7 && s > 0) {
      floatx4 oa = {0,0,0,0}, ob = {0,0,0,0};
      const char* bprev = base + s3p * 16384;
#pragma unroll
      for (int kt = 0; kt < 16; kt += 2) {
        const half8 f0 = *(const half8*)(bprev + kt * 1024 + lane * 16);
        const half8 f1 = *(const half8*)(bprev + (kt + 1) * 1024 + lane * 16);
        oa = MFMA16(f0, ws_wout[kt][lane], oa);
        ob = MFMA16(f1, ws_wout[kt + 1][lane], ob);
      }
      if (l15 < kO) {
#pragma unroll
        for (int q = 0; q < 4; ++q)
          out[((size_t)(g * 16 + lhi * 4 + q) * kS + (s - 1)) * kO + l15] = oa[q] + ob[q];
      }
    }

    // prefetch noise row s + inp row s+1 (ride free under the flag wait)
    float nz0[4], nz1[4];
    float invN = 0.f;
    if (!lastS) {
#pragma unroll
      for (int q = 0; q < 4; ++q) {
        const int b = g * 16 + lhi * 4 + q;
        nz0[q] = noise[((size_t)b * kS + s) * kH + j0];
        nz1[q] = noise[((size_t)b * kS + s) * kH + j1];
      }
    }
    if (s < kS - 2 && (w == 2 || w == 3)) {
      const int ii = tid - 128;
      invN = inp[((size_t)(g * 16 + (ii >> 3)) * kS + (s + 1)) * kI + (ii & 7)];
    }

    // poll single peer flag (>= s+1); agent-scope (proven; sc0 polls hang)
    {
      const unsigned need = (unsigned)(s + 1);
      const unsigned* fp = &flags[(cur * GROUPS + g) * NSPL + (c ^ 1)];
      while ((ld_flag(fp) & 0xffffu) < need) {}
      asm volatile("" ::: "memory");
    }

    // issue peer loads: staging 16B (pv) + the FULL peer half per wave.
    // 13-bit signed offset limit: two bases (srcrf, srcrf+4096), offs 0..3072.
    uintx4 pv;
    half8 rf0, rf1, rf2, rf3, rf4, rf5, rf6, rf7;
    {
      const char* phalf = (const char*)rbuf + (size_t)(cur * GROUPS + g) * (RSLOT * 2)
                          + (c ^ 1) * 8192;
      const char* srcpv = phalf + tid * 16;
      const char* srcrf = phalf + lane * 16;
      const char* srcrh = srcrf + 4096;
      if (sameXcd) {
        asm volatile("global_load_dwordx4 %0, %1, off sc0" : "=&v"(pv) : "v"(srcpv) : "memory");
        asm volatile(
          "global_load_dwordx4 %0, %4, off sc0\n\t"
          "global_load_dwordx4 %1, %4, off offset:1024 sc0\n\t"
          "global_load_dwordx4 %2, %4, off offset:2048 sc0\n\t"
          "global_load_dwordx4 %3, %4, off offset:3072 sc0"
          : "=&v"(rf0), "=&v"(rf1), "=&v"(rf2), "=&v"(rf3)
          : "v"(srcrf) : "memory");
        asm volatile(
          "global_load_dwordx4 %0, %4, off sc0\n\t"
          "global_load_dwordx4 %1, %4, off offset:1024 sc0\n\t"
          "global_load_dwordx4 %2, %4, off offset:2048 sc0\n\t"
          "global_load_dwordx4 %3, %4, off offset:3072 sc0"
          : "=&v"(rf4), "=&v"(rf5), "=&v"(rf6), "=&v"(rf7)
          : "v"(srcrh) : "memory");
      } else {
        asm volatile("global_load_dwordx4 %0, %1, off sc0 sc1" : "=&v"(pv) : "v"(srcpv) : "memory");
        asm volatile(
          "global_load_dwordx4 %0, %4, off sc0 sc1\n\t"
          "global_load_dwordx4 %1, %4, off offset:1024 sc0 sc1\n\t"
          "global_load_dwordx4 %2, %4, off offset:2048 sc0 sc1\n\t"
          "global_load_dwordx4 %3, %4, off offset:3072 sc0 sc1"
          : "=&v"(rf0), "=&v"(rf1), "=&v"(rf2), "=&v"(rf3)
          : "v"(srcrf) : "memory");
        asm volatile(
          "global_load_dwordx4 %0, %4, off sc0 sc1\n\t"
          "global_load_dwordx4 %1, %4, off offset:1024 sc0 sc1\n\t"
          "global_load_dwordx4 %2, %4, off offset:2048 sc0 sc1\n\t"
          "global_load_dwordx4 %3, %4, off offset:3072 sc0 sc1"
          : "=&v"(rf4), "=&v"(rf5), "=&v"(rf6), "=&v"(rf7)
          : "v"(srcrh) : "memory");
      }
    }

    // A-phase: own k-half (8 kt) from LDS slot s3c; weight regs static
    floatx4 a00 = {0,0,0,0}, a01 = {0,0,0,0}, a10 = {0,0,0,0}, a11 = {0,0,0,0};
    const char* bA = base + s3c * 16384;
    const char* baseO = bA + c * 8192;
#pragma unroll
    for (int t = 0; t < 8; t += 2) {
      const half8 f0 = *(const half8*)(baseO + t * 1024 + lane * 16);
      const half8 f1 = *(const half8*)(baseO + (t + 1) * 1024 + lane * 16);
      a00 = MFMA16(f0, wfo0[t], a00);
      a10 = MFMA16(f0, wfo1[t], a10);
      a01 = MFMA16(f1, wfo0[t + 1], a01);
      a11 = MFMA16(f1, wfo1[t + 1], a11);
    }
    __builtin_amdgcn_sched_barrier(0);
    // count-free drain: pv + 8 rf + noise/inp all complete here
    asm volatile("s_waitcnt vmcnt(0)"
                 : "+v"(pv), "+v"(rf0), "+v"(rf1), "+v"(rf2), "+v"(rf3),
                   "+v"(rf4), "+v"(rf5), "+v"(rf6), "+v"(rf7) :: "memory");
    __builtin_amdgcn_sched_barrier(0);  // rule 18: MFMAs stay behind the drain
    // stage peer 16B into slot s3c (for w7's out-GEMM next step / epilogue)
    *(uintx4*)((char*)base + s3c * 16384 + (c ^ 1) * 8192 + tid * 16) = pv;
    // stage inp row s+1 (read at D(s+1), ordered by barD(s))
    if (s < kS - 2 && (w == 2 || w == 3)) {
      const int ii = tid - 128;
      ldsIN[(s + 1) & 1][ii >> 3][ii & 7] = invN;
    }

    // C-phase: peer k-half register-direct (no LDS, no barrier)
    a00 = MFMA16(rf0, wfp0[0], a00);
    a10 = MFMA16(rf0, wfp1[0], a10);
    a01 = MFMA16(rf1, wfp0[1], a01);
    a11 = MFMA16(rf1, wfp1[1], a11);
    a00 = MFMA16(rf2, wfp0[2], a00);
    a10 = MFMA16(rf2, wfp1[2], a10);
    a01 = MFMA16(rf3, wfp0[3], a01);
    a11 = MFMA16(rf3, wfp1[3], a11);
    a00 = MFMA16(rf4, wfp0[4], a00);
    a10 = MFMA16(rf4, wfp1[4], a10);
    a01 = MFMA16(rf5, wfp0[5], a01);
    a11 = MFMA16(rf5, wfp1[5], a11);
    a00 = MFMA16(rf6, wfp0[6], a00);
    a10 = MFMA16(rf6, wfp1[6], a10);
    a01 = MFMA16(rf7, wfp0[7], a01);
    a11 = MFMA16(rf7, wfp1[7], a11);

    // D-phase: h update (noise row s, ldsIN[s&1] = inp row s), write r_{s+1}
    // own chunk into slot s3n, publish own chunk
    if (!lastS) {
      _Float16* lA = &ldsA[0][0] + s3n * RSLOT;
#pragma unroll
      for (int q = 0; q < 4; ++q) {
        const int bb = lhi * 4 + q;
        const floatx4 iv0 = *(const floatx4*)&ldsIN[s & 1][bb][0];
        const floatx4 iv1 = *(const floatx4*)&ldsIN[s & 1][bb][4];
        float x0 = 0.f, x1 = 0.f;
#pragma unroll
        for (int i = 0; i < 4; ++i) {
          x0 = fmaf(iv0[i], wiv0[i], x0); x0 = fmaf(iv1[i], wiv0[i + 4], x0);
          x1 = fmaf(iv0[i], wiv1[i], x1); x1 = fmaf(iv1[i], wiv1[i + 4], x1);
        }
        const float y0 = a00[q] + a01[q], y1 = a10[q] + a11[q];
        const float h0n = hq0[q] + kNoiseStd * nz0[q] + kAlpha * (-hq0[q] + y0 + x0);
        const float h1n = hq1[q] + kNoiseStd * nz1[q] + kAlpha * (-hq1[q] + y1 + x1);
        hq0[q] = h0n; hq1[q] = h1n;
        lA[ktp * 512 + (bb + 16 * jsub0) * 8 + vv] = (_Float16)fast_tanh(h0n);
        lA[ktp * 512 + (bb + 16 * jsub1) * 8 + vv] = (_Float16)fast_tanh(h1n);
      }
      // publish this wave's 1KB chunk (same-wave LDS write->read; lgkm ordered)
      const uintx4 pub = *(const uintx4*)((const char*)lA + ktp * 1024 + lane * 16);
      char* dst = (char*)rbuf + (size_t)((cur ^ 1) * GROUPS + g) * (RSLOT * 2)
                  + ktp * 1024 + lane * 16;
      if (sameXcd)
        asm volatile("global_store_dwordx4 %0, %1, off sc0" :: "v"(dst), "v"(pub) : "memory");
      else
        asm volatile("global_store_dwordx4 %0, %1, off sc0 sc1" :: "v"(dst), "v"(pub) : "memory");
    }
    __syncthreads();  // barD: drains publish stores (vmcnt 0) + LDS writes
    if (!lastS && tid == 0)
      st_flag(&flags[((cur ^ 1) * GROUPS + g) * NSPL + c], (unsigned)(s + 2));

    const int t3 = s3p; s3p = s3c; s3c = s3n; s3n = t3;
  }

  // epilogue: out row kS-1 from ldsA slot (kS-1)%3 = 1 (own half from D(1998),
  // peer half staged at s=1999; D(1999) skipped so both halves intact)
  if (c == 0 && w == 7) {
    const char* bfin = base + ((kS - 1) % 3) * 16384;
    floatx4 oa = {0,0,0,0}, ob = {0,0,0,0};
#pragma unroll
    for (int kt = 0; kt < 16; kt += 2) {
      const half8 f0 = *(const half8*)(bfin + kt * 1024 + lane * 16);
      const half8 f1 = *(const half8*)(bfin + (kt + 1) * 1024 + lane * 16);
      oa = MFMA16(f0, ws_wout[kt][lane], oa);
      ob = MFMA16(f1, ws_wout[kt + 1][lane], ob);
    }
    if (l15 < kO) {
#pragma unroll
      for (int q = 0; q < 4; ++q)
        out[((size_t)(g * 16 + lhi * 4 + q) * kS + (kS - 1)) * kO + l15] = oa[q] + ob[q];
    }
  }
}

extern "C" void kernel_launch(void* const* d_in, const int* in_sizes, int n_in,
                              void* d_out, int out_size, void* d_ws, size_t ws_size,
                              hipStream_t stream) {
  const float* inp   = (const float*)d_in[0];
  const float* noise = (const float*)d_in[1];
  const float* wi    = (const float*)d_in[2];
  const float* wexc  = (const float*)d_in[3];
  const float* winh  = (const float*)d_in[4];
  const float* wout  = (const float*)d_in[5];
  const float* h0    = (const float*)d_in[6];

  _Float16* rbuf = (_Float16*)d_ws;  // 2 slots x 8 groups x 16KB = 256KB
  const size_t rbytes = (size_t)2 * GROUPS * RSLOT * sizeof(_Float16);
  unsigned* flags = (unsigned*)((char*)d_ws + rbytes);  // 32 words

  hipMemsetAsync(flags, 0, 2 * GROUPS * NSPL * sizeof(unsigned), stream);
  rnn_k<<<NBLK, NTHR, 0, stream>>>(inp, noise, wi, wexc, winh, wout, h0,
                                   (float*)d_out, rbuf, flags);
}